// Round 2
// baseline (2143.719 us; speedup 1.0000x reference)
//
#include <hip/hip_runtime.h>
#include <hip/hip_bf16.h>

// Problem constants: x[B=256][T=2048][I=256], W_ih[256][256], W_hh[256][256],
// b_h[256], fc_w[16][256], fc_b[16]. out[256][16] fp32.

typedef _Float16 f16;
typedef _Float16 h8_t __attribute__((ext_vector_type(8)));
typedef _Float16 h2_t __attribute__((ext_vector_type(2)));
typedef float    f4_t __attribute__((ext_vector_type(4)));

__device__ __forceinline__ float fdot2u(unsigned w, unsigned h, float c) {
  return __builtin_amdgcn_fdot2(__builtin_bit_cast(h2_t, w),
                                __builtin_bit_cast(h2_t, h), c, false);
}

__device__ __forceinline__ unsigned pkrtz(float a, float b) {
  return __builtin_bit_cast(unsigned, __builtin_amdgcn_cvt_pkrtz(a, b));
}

// ---------------------------------------------------------------------------
// Prep: Wt[n][k] = (f16)W_ih[k][n]  (B-operand, contiguous in k for frag loads)
//       Wc[j][p] = packed f16 pair (W_hh[2p][j], W_hh[2p+1][j])  (dot2 operand)
// ---------------------------------------------------------------------------
__global__ __launch_bounds__(256) void prep_kernel(const float* __restrict__ Wih,
                                                   const float* __restrict__ Whh,
                                                   f16* __restrict__ Wt,
                                                   unsigned* __restrict__ Wc) {
  int idx = blockIdx.x * 256 + threadIdx.x;
  if (idx < 65536) {
    int n = idx >> 8, k = idx & 255;
    Wt[n * 256 + k] = (f16)Wih[k * 256 + n];
  } else {
    int p = idx - 65536;          // 0..32767
    int j = p >> 7, pp = p & 127;
    Wc[j * 128 + pp] = pkrtz(Whh[(2 * pp) * 256 + j], Whh[(2 * pp + 1) * 256 + j]);
  }
}

// ---------------------------------------------------------------------------
// GEMM: xp[t-t0][b][n] = sum_k x[b][t][k] * W_ih[k][n], f16 out.
// mfma_f32_16x16x32_f16. A from global x (fp32->f16 cvt), B persistent in regs.
// Block tile: 64 rows (b) x 256 cols; wave w owns ntiles 4w..4w+3, all 4 mtiles.
// ---------------------------------------------------------------------------
__global__ __launch_bounds__(256, 2) void gemm_kernel(const float* __restrict__ x,
                                                      const f16* __restrict__ Wt,
                                                      f16* __restrict__ xp,
                                                      int t0, int CT) {
  int tid = threadIdx.x;
  int wave = tid >> 6, lane = tid & 63;
  int l15 = lane & 15, q = lane >> 4;

  // B fragments: bf[nt][ks], lane holds Wt[n= (4w+nt)*16+l15][k = 32ks+8q .. +7]
  uint4 bf[4][8];
#pragma unroll
  for (int nt = 0; nt < 4; ++nt) {
    int n = (wave * 4 + nt) * 16 + l15;
    const uint4* bp = (const uint4*)(Wt + (size_t)n * 256 + q * 8);
#pragma unroll
    for (int ks = 0; ks < 8; ++ks) bf[nt][ks] = bp[ks * 4];  // +64B per kstep
  }

  int tiles = CT * 4;
  for (int tile = blockIdx.x; tile < tiles; tile += gridDim.x) {
    int tl = tile >> 2;            // t - t0
    int t = t0 + tl;
    int b0 = (tile & 3) << 6;
    size_t obase = (size_t)tl * 65536;

    for (int mt = 0; mt < 4; ++mt) {
      int row = b0 + mt * 16 + l15;                       // A row = batch index
      const float* xr = x + ((size_t)row * 2048 + t) * 256 + q * 8;
      f4_t acc[4];
#pragma unroll
      for (int nt = 0; nt < 4; ++nt) acc[nt] = (f4_t){0.f, 0.f, 0.f, 0.f};

#pragma unroll
      for (int ks = 0; ks < 8; ++ks) {
        float4 f0 = *(const float4*)(xr + ks * 32);
        float4 f1 = *(const float4*)(xr + ks * 32 + 4);
        uint4 au;
        au.x = pkrtz(f0.x, f0.y);
        au.y = pkrtz(f0.z, f0.w);
        au.z = pkrtz(f1.x, f1.y);
        au.w = pkrtz(f1.z, f1.w);
        h8_t a = __builtin_bit_cast(h8_t, au);
#pragma unroll
        for (int nt = 0; nt < 4; ++nt)
          acc[nt] = __builtin_amdgcn_mfma_f32_16x16x32_f16(
              a, __builtin_bit_cast(h8_t, bf[nt][ks]), acc[nt], 0, 0, 0);
      }
      // D layout (verified): row = 4*q + r, col = l15 within each 16x16 tile
#pragma unroll
      for (int nt = 0; nt < 4; ++nt) {
        int n = (wave * 4 + nt) * 16 + l15;
#pragma unroll
        for (int r = 0; r < 4; ++r) {
          int brow = b0 + mt * 16 + q * 4 + r;
          xp[obase + (size_t)brow * 256 + n] = (f16)acc[nt][r];
        }
      }
    }
  }
}

// ---------------------------------------------------------------------------
// Recurrence: 256 blocks (one batch chain per CU), 256 threads (one h-column
// each). W column in VGPRs (128 f16x2 pairs). h broadcast via LDS (f16,
// double-buffered). 128 v_dot2_f32_f16 per step, fp32 accum, fp32 tanh.
// ---------------------------------------------------------------------------
__global__ __launch_bounds__(256) void rnn_kernel(const f16* __restrict__ xp,
                                                  const unsigned* __restrict__ Wc,
                                                  const float* __restrict__ b_h,
                                                  const float* __restrict__ fc_w,
                                                  const float* __restrict__ fc_b,
                                                  float* __restrict__ hstate,
                                                  float* __restrict__ out,
                                                  int t0, int CT) {
  __shared__ uint4 hls[2][32];          // 2 x 256 f16
  __shared__ float hf[256];
  __shared__ float prt[16][16];

  int b = blockIdx.x, j = threadIdx.x;

  uint4 wv[32];                          // 128 packed pairs of W_hh[:,j]
  const uint4* wp = (const uint4*)(Wc + (size_t)j * 128);
#pragma unroll
  for (int p = 0; p < 32; ++p) wv[p] = wp[p];

  float hcur = (t0 == 0) ? 0.0f : hstate[b * 256 + j];
  ((f16*)hls[0])[j] = (f16)hcur;
  float bhv = b_h[j];

  const f16* xpb = xp + b * 256 + j;     // stride per step = 65536
  float xv = (float)xpb[0];
  float xn = (float)xpb[65536];          // CT >= 2 always
  __syncthreads();

  for (int tt = 0; tt < CT; ++tt) {
    int pf = (tt + 2 < CT) ? tt + 2 : CT - 1;
    f16 xf = xpb[(size_t)pf * 65536];    // prefetch 2 ahead

    const uint4* hb = hls[tt & 1];
    float a0 = 0.f, a1 = 0.f, a2 = 0.f, a3 = 0.f;
    float a4 = 0.f, a5 = 0.f, a6 = 0.f, a7 = 0.f;
#pragma unroll
    for (int p = 0; p < 32; p += 2) {    // 8 indep. accumulation chains
      uint4 hv0 = hb[p];
      uint4 hv1 = hb[p + 1];
      a0 = fdot2u(wv[p].x, hv0.x, a0);
      a1 = fdot2u(wv[p].y, hv0.y, a1);
      a2 = fdot2u(wv[p].z, hv0.z, a2);
      a3 = fdot2u(wv[p].w, hv0.w, a3);
      a4 = fdot2u(wv[p + 1].x, hv1.x, a4);
      a5 = fdot2u(wv[p + 1].y, hv1.y, a5);
      a6 = fdot2u(wv[p + 1].z, hv1.z, a6);
      a7 = fdot2u(wv[p + 1].w, hv1.w, a7);
    }
    float z = (((a0 + a1) + (a2 + a3)) + ((a4 + a5) + (a6 + a7))) + xv + bhv;
    // tanh(z) = 1 - 2/(exp(2z)+1)
    float e = __expf(2.0f * z);
    hcur = 1.0f - 2.0f * __builtin_amdgcn_rcpf(e + 1.0f);
    ((f16*)hls[(tt + 1) & 1])[j] = (f16)hcur;
    xv = xn;
    xn = (float)xf;
    __syncthreads();
  }

  hstate[b * 256 + j] = hcur;            // carry fp32 state across chunks

  if (t0 + CT == 2048) {                 // fused classifier head (fp32)
    hf[j] = hcur;
    __syncthreads();
    int o = j >> 4, s = j & 15;
    const float* fw = fc_w + o * 256 + s * 16;
    float p = 0.f;
#pragma unroll
    for (int i = 0; i < 16; ++i) p += hf[s * 16 + i] * fw[i];
    prt[o][s] = p;
    __syncthreads();
    if (j < 16) {
      float r = fc_b[j];
#pragma unroll
      for (int s2 = 0; s2 < 16; ++s2) r += prt[j][s2];
      out[b * 16 + j] = r;
    }
  }
}

// ---------------------------------------------------------------------------
extern "C" void kernel_launch(void* const* d_in, const int* in_sizes, int n_in,
                              void* d_out, int out_size, void* d_ws, size_t ws_size,
                              hipStream_t stream) {
  const float* x   = (const float*)d_in[0];
  const float* Wih = (const float*)d_in[1];
  const float* Whh = (const float*)d_in[2];
  const float* bh  = (const float*)d_in[3];
  const float* fcw = (const float*)d_in[4];
  const float* fcb = (const float*)d_in[5];
  float* out = (float*)d_out;

  char* ws = (char*)d_ws;
  f16*      Wt     = (f16*)ws;                       // 128 KB
  unsigned* Wc     = (unsigned*)(ws + (128 << 10));  // 128 KB
  float*    hstate = (float*)(ws + (256 << 10));     // 256 KB
  f16*      xpb    = (f16*)(ws + (512 << 10));       // chunk buffer

  size_t avail = (ws_size > (size_t)(512 << 10)) ? ws_size - (size_t)(512 << 10) : 0;
  int CT = 2048;                                     // xp chunk length (steps)
  while (CT > 16 && (size_t)CT * 65536 * 2 > avail) CT >>= 1;

  prep_kernel<<<384, 256, 0, stream>>>(Wih, Whh, Wt, Wc);
  for (int t0 = 0; t0 < 2048; t0 += CT) {
    gemm_kernel<<<512, 256, 0, stream>>>(x, Wt, xpb, t0, CT);
    rnn_kernel<<<256, 256, 0, stream>>>(xpb, Wc, bh, fcw, fcb, hstate, out, t0, CT);
  }
}

// Round 3
// 1969.390 us; speedup vs baseline: 1.0885x; 1.0885x over previous
//
#include <hip/hip_runtime.h>
#include <hip/hip_bf16.h>

// B=256, T=2048, I=H=256, O=16. fp32 in/out. xp kept f16 as [b][t][n].

typedef _Float16 f16;
typedef _Float16 h8_t __attribute__((ext_vector_type(8)));
typedef _Float16 h2_t __attribute__((ext_vector_type(2)));
typedef float    f4_t __attribute__((ext_vector_type(4)));

__device__ __forceinline__ float fdot2u(unsigned w, unsigned h, float c) {
  return __builtin_amdgcn_fdot2(__builtin_bit_cast(h2_t, w),
                                __builtin_bit_cast(h2_t, h), c, false);
}
__device__ __forceinline__ unsigned pkrtz(float a, float b) {
  return __builtin_bit_cast(unsigned, __builtin_amdgcn_cvt_pkrtz(a, b));
}

// ---------------------------------------------------------------------------
// prep: Wfrag = W_ih in exact MFMA B-fragment order (coalesced preload),
//       Wc2   = W_hh packed f16-pairs in rnn per-lane granule order.
// Wfrag[(nt*8+ks)*256 + (w*64+l)] : 8 f16 = Wih[k][n], k=ks*32+(l>>4)*8+j,
//   n = w*64+nt*16+(l&15).
// Wc2[(oi*8+q2)*256 + (w*64+l)]   : pairs pp=q2*4+c of k-slice 64w for
//   output j=l+64*oi: pack(Whh[64w+2pp][j], Whh[64w+2pp+1][j]).
// ---------------------------------------------------------------------------
__global__ __launch_bounds__(256) void prep_kernel(const float* __restrict__ Wih,
                                                   const float* __restrict__ Whh,
                                                   uint4* __restrict__ Wfrag,
                                                   uint4* __restrict__ Wc2) {
  int idx = blockIdx.x * 256 + threadIdx.x;   // 0..16383
  int e = idx & 8191;
  int gi = e >> 8;          // 0..31
  int lg = e & 255;         // w*64+l
  int w = lg >> 6, l = lg & 63;
  unsigned r[4];
  if (idx < 8192) {
    int nt = gi >> 3, ks = gi & 7;
    int n = w * 64 + nt * 16 + (l & 15);
    int k0 = ks * 32 + (l >> 4) * 8;
#pragma unroll
    for (int c = 0; c < 4; ++c)
      r[c] = pkrtz(Wih[(k0 + 2 * c) * 256 + n], Wih[(k0 + 2 * c + 1) * 256 + n]);
    Wfrag[gi * 256 + lg] = make_uint4(r[0], r[1], r[2], r[3]);
  } else {
    int oi = gi >> 3, q2 = gi & 7;
    int j = l + 64 * oi;
    int kb = 64 * w + 8 * q2;
#pragma unroll
    for (int c = 0; c < 4; ++c)
      r[c] = pkrtz(Whh[(kb + 2 * c) * 256 + j], Whh[(kb + 2 * c + 1) * 256 + j]);
    Wc2[gi * 256 + lg] = make_uint4(r[0], r[1], r[2], r[3]);
  }
}

// ---------------------------------------------------------------------------
// GEMM: block = (batch b, 64-step t-tile). x tile is 64KB CONTIGUOUS fp32:
// coalesced load -> f16 -> padded LDS. W frags persistent in VGPRs (coalesced
// preload from Wfrag). 128 MFMA/wave. xp[b][t][n] f16 out.
// ---------------------------------------------------------------------------
__global__ __launch_bounds__(256, 2) void gemm_kernel(const float* __restrict__ x,
                                                      const uint4* __restrict__ Wfrag,
                                                      f16* __restrict__ xp,
                                                      int t0, int CT, int tpc) {
  __shared__ f16 As[64][264];                 // +8 f16 pad per row
  int tid = threadIdx.x;
  int wave = tid >> 6, l = tid & 63, l15 = l & 15, q = l >> 4;

  uint4 bf[4][8];
#pragma unroll
  for (int nt = 0; nt < 4; ++nt)
#pragma unroll
    for (int ks = 0; ks < 8; ++ks)
      bf[nt][ks] = Wfrag[(nt * 8 + ks) * 256 + tid];

  int blk = blockIdx.x;
  int b = blk / tpc, tt = blk - b * tpc;
  int tl0 = tt * 64;

  const uint4* xsrc = (const uint4*)(x + ((size_t)b * 2048 + t0 + tl0) * 256);
#pragma unroll
  for (int i = 0; i < 16; ++i) {              // 64KB tile: 16 uint4/thread
    int fi = i * 256 + tid;
    float4 f = __builtin_bit_cast(float4, xsrc[fi]);
    int row = fi >> 6;                        // t-row 0..63
    int k = (fi & 63) * 4;
    uint2 pv; pv.x = pkrtz(f.x, f.y); pv.y = pkrtz(f.z, f.w);
    *(uint2*)&As[row][k] = pv;
  }
  __syncthreads();

  f4_t acc[4][4];
#pragma unroll
  for (int mt = 0; mt < 4; ++mt)
#pragma unroll
    for (int nt = 0; nt < 4; ++nt) acc[mt][nt] = (f4_t){0.f, 0.f, 0.f, 0.f};

  for (int mt = 0; mt < 4; ++mt) {
    uint4 af[8];
#pragma unroll
    for (int ks = 0; ks < 8; ++ks)
      af[ks] = *(const uint4*)&As[mt * 16 + l15][ks * 32 + q * 8];
#pragma unroll
    for (int ks = 0; ks < 8; ++ks) {
      h8_t a = __builtin_bit_cast(h8_t, af[ks]);
#pragma unroll
      for (int nt = 0; nt < 4; ++nt)
        acc[mt][nt] = __builtin_amdgcn_mfma_f32_16x16x32_f16(
            a, __builtin_bit_cast(h8_t, bf[nt][ks]), acc[mt][nt], 0, 0, 0);
    }
  }

  f16* xpo = xp + (size_t)b * CT * 256;       // xp[b][tl][n]
#pragma unroll
  for (int mt = 0; mt < 4; ++mt)
#pragma unroll
    for (int nt = 0; nt < 4; ++nt) {
      int n = wave * 64 + nt * 16 + l15;
#pragma unroll
      for (int r = 0; r < 4; ++r)
        xpo[(size_t)(tl0 + mt * 16 + q * 4 + r) * 256 + n] = (f16)acc[mt][nt][r];
    }
}

// ---------------------------------------------------------------------------
// RNN: 256 blocks (1 batch/CU) x 256 threads. K-split by wave: wave w owns
// k in [64w,64w+64) for ALL 256 outputs (4 outputs/lane, 128 dot2/lane).
// h broadcast read = 8 ds_read_b128/lane (128B slice). Partials via LDS.
// __launch_bounds__(256,1): 512-VGPR budget keeps 128-reg weight array live.
// ---------------------------------------------------------------------------
__global__ __launch_bounds__(256, 1) void rnn_kernel(const f16* __restrict__ xp,
                                                     const uint4* __restrict__ Wc2,
                                                     const float* __restrict__ b_h,
                                                     const float* __restrict__ fc_w,
                                                     const float* __restrict__ fc_b,
                                                     float* __restrict__ hstate,
                                                     float* __restrict__ out,
                                                     int t0, int CT) {
  __shared__ f16 hbuf[2][256];
  __shared__ float prt[4][256];
  __shared__ float hf[256];
  __shared__ float prt2[16][16];

  int b = blockIdx.x, tid = threadIdx.x;
  int w = tid >> 6, l = tid & 63;

  uint4 wv[32];                                // 128 VGPRs of W_hh granules
#pragma unroll
  for (int g = 0; g < 32; ++g) wv[g] = Wc2[g * 256 + tid];

  float hcur = (t0 == 0) ? 0.0f : hstate[b * 256 + tid];
  hbuf[0][tid] = (f16)hcur;
  float bhv = b_h[tid];

  const f16* xpb = xp + (size_t)b * CT * 256 + tid;
  float xv = (float)xpb[0];
  float xn = (float)xpb[256];
  __syncthreads();

  for (int tt = 0; tt < CT; ++tt) {
    int pf = (tt + 2 < CT) ? tt + 2 : CT - 1;
    f16 xf = xpb[(size_t)pf * 256];            // prefetch 2 ahead

    const uint4* hb = (const uint4*)&hbuf[tt & 1][w * 64];
    uint4 hh[8];
#pragma unroll
    for (int q2 = 0; q2 < 8; ++q2) hh[q2] = hb[q2];   // broadcast, 128B

    float s[4];
#pragma unroll
    for (int oi = 0; oi < 4; ++oi) {
      float a0 = 0.f, a1 = 0.f;
#pragma unroll
      for (int q2 = 0; q2 < 8; ++q2) {
        uint4 wq = wv[oi * 8 + q2];
        a0 = fdot2u(wq.x, hh[q2].x, a0);
        a1 = fdot2u(wq.y, hh[q2].y, a1);
        a0 = fdot2u(wq.z, hh[q2].z, a0);
        a1 = fdot2u(wq.w, hh[q2].w, a1);
      }
      s[oi] = a0 + a1;
    }
#pragma unroll
    for (int oi = 0; oi < 4; ++oi) prt[w][l + 64 * oi] = s[oi];
    __syncthreads();

    float z = prt[0][tid] + prt[1][tid] + prt[2][tid] + prt[3][tid] + xv + bhv;
    float e = __expf(2.0f * z);
    hcur = 1.0f - 2.0f * __builtin_amdgcn_rcpf(e + 1.0f);   // tanh(z)
    hbuf[(tt + 1) & 1][tid] = (f16)hcur;
    xv = xn;
    xn = (float)xf;
    __syncthreads();
  }

  hstate[b * 256 + tid] = hcur;

  if (t0 + CT == 2048) {                       // fused fp32 classifier head
    hf[tid] = hcur;
    __syncthreads();
    int o = tid >> 4, s2 = tid & 15;
    const float* fw = fc_w + o * 256 + s2 * 16;
    float p = 0.f;
#pragma unroll
    for (int i = 0; i < 16; ++i) p += hf[s2 * 16 + i] * fw[i];
    prt2[o][s2] = p;
    __syncthreads();
    if (tid < 16) {
      float r = fc_b[tid];
#pragma unroll
      for (int s3 = 0; s3 < 16; ++s3) r += prt2[tid][s3];
      out[b * 16 + tid] = r;
    }
  }
}

// ---------------------------------------------------------------------------
extern "C" void kernel_launch(void* const* d_in, const int* in_sizes, int n_in,
                              void* d_out, int out_size, void* d_ws, size_t ws_size,
                              hipStream_t stream) {
  const float* x   = (const float*)d_in[0];
  const float* Wih = (const float*)d_in[1];
  const float* Whh = (const float*)d_in[2];
  const float* bh  = (const float*)d_in[3];
  const float* fcw = (const float*)d_in[4];
  const float* fcb = (const float*)d_in[5];
  float* out = (float*)d_out;

  char* ws = (char*)d_ws;
  uint4* Wfrag  = (uint4*)ws;                        // 128 KB
  uint4* Wc2    = (uint4*)(ws + (128 << 10));        // 128 KB
  float* hstate = (float*)(ws + (256 << 10));        // 256 KB
  f16*   xpb    = (f16*)(ws + (512 << 10));          // chunk buffer

  size_t avail = (ws_size > (size_t)(512 << 10)) ? ws_size - (size_t)(512 << 10) : 0;
  int CT = 2048;
  while (CT > 64 && (size_t)CT * 131072 > avail) CT >>= 1;
  int tpc = CT >> 6;                                 // 64-step tiles per chunk

  prep_kernel<<<64, 256, 0, stream>>>(Wih, Whh, Wfrag, Wc2);
  for (int t0 = 0; t0 < 2048; t0 += CT) {
    gemm_kernel<<<256 * tpc, 256, 0, stream>>>(x, Wfrag, xpb, t0, CT, tpc);
    rnn_kernel<<<256, 256, 0, stream>>>(xpb, Wc2, bh, fcw, fcb, hstate, out, t0, CT);
  }
}